// Round 11
// baseline (3721.754 us; speedup 1.0000x reference)
//
#include <hip/hip_runtime.h>
#include <hip/hip_fp16.h>

#define N_NODES 10000
#define N_EDGES 60000
#define EPAD    60032   // multiple of 128
#define CSPLIT  2
#define CT_PER  32      // 64 / CSPLIT
#define NGROUPS 4       // CT_PER / 8

typedef _Float16 f16;
typedef f16 f16x8 __attribute__((ext_vector_type(8)));
typedef float f32x4 __attribute__((ext_vector_type(4)));

__device__ __forceinline__ void gload16(const void* g, void* l) {
    __builtin_amdgcn_global_load_lds((const __attribute__((address_space(1))) unsigned int*)g,
                                     (__attribute__((address_space(3))) unsigned int*)l, 16, 0, 0);
}

// select-then-pair-sum: bit-clear lanes end with a_l + a_{l^m}; bit-set with b_l + b_{l^m}
__device__ __forceinline__ float foldp(float a, float b, int m, int lane) {
    float x = (lane & m) ? b : a;
    float y = (lane & m) ? a : b;
    return x + __shfl_xor(y, m);
}

// ---------------- node encoder: h = relu(x@nW1+nb1)@nW2+nb2 ----------------
__global__ void k_node_enc(const float* __restrict__ x, const float* __restrict__ W1,
                           const float* __restrict__ b1, const float* __restrict__ W2,
                           const float* __restrict__ b2, float* __restrict__ h) {
    __shared__ float t[4][64];
    int g = threadIdx.x >> 6, j = threadIdx.x & 63;
    int node = blockIdx.x * 4 + g;
    float acc = b1[j];
#pragma unroll
    for (int i = 0; i < 6; ++i) acc += x[node * 6 + i] * W1[i * 64 + j];
    t[g][j] = fmaxf(acc, 0.f);
    __syncthreads();
    float acc2 = b2[j];
#pragma unroll
    for (int i = 0; i < 64; ++i) acc2 += t[g][i] * W2[i * 64 + j];
    h[node * 64 + j] = acc2;
}

// ---------------- condition encoder -----------------------------------------
__global__ void k_cond_enc(const float* __restrict__ cond, const float* __restrict__ scl,
                           const float* __restrict__ W1, const float* __restrict__ b1,
                           const float* __restrict__ W2, const float* __restrict__ b2,
                           float* __restrict__ u, float* __restrict__ out_u) {
    __shared__ float t[4][64];
    __shared__ float cat[4][14];
    int g = threadIdx.x >> 6, j = threadIdx.x & 63;
    if (threadIdx.x < 56) {
        int b = threadIdx.x / 14, i = threadIdx.x % 14;
        cat[b][i] = (i < 10) ? cond[b * 10 + i] : scl[b * 4 + (i - 10)];
    }
    __syncthreads();
    float acc = b1[j];
#pragma unroll
    for (int i = 0; i < 14; ++i) acc += cat[g][i] * W1[i * 64 + j];
    t[g][j] = fmaxf(acc, 0.f);
    __syncthreads();
    float acc2 = b2[j];
#pragma unroll
    for (int i = 0; i < 64; ++i) acc2 += t[g][i] * W2[i * 64 + j];
    u[g * 64 + j] = acc2;
    out_u[g * 64 + j] = acc2;
}

// ---------------- degree -----------------------------------------------------
__global__ void k_deg(const int* __restrict__ dst, float* __restrict__ deg) {
    int e = blockIdx.x * 256 + threadIdx.x;
    if (e < N_EDGES) atomicAdd(&deg[dst[e]], 1.0f);
}
__global__ void k_deg_inv(float* __restrict__ deg) {
    int n = blockIdx.x * 256 + threadIdx.x;
    if (n < N_NODES) deg[n] = 1.0f / fmaxf(deg[n], 1.0f);
}

// ------- permute kW3 into FRAGMENT-ORDERED K-HALF tiles + kb3P ---------------
// tile t = ct*2 + kh (16 KB each): offset = t*8192 + ((nf*4+ks4)*64 + kg*16 + rl)*8
// element j there = kW3[k][i*64+ct] with i=nf*16+rl, k=kh*128 + ks4*32 + kg*8 + j
__global__ void k_permute(const float* __restrict__ kW3, const float* __restrict__ kb3,
                          f16* __restrict__ kW3P, float* __restrict__ kb3P) {
    __shared__ float T[256][65];
    int i = blockIdx.x;                 // 0..63 (inner input index)
    int o = threadIdx.x & 63, kq = threadIdx.x >> 6;
    for (int kk = 0; kk < 64; ++kk) {
        int k = kk * 4 + kq;
        T[k][o] = kW3[(size_t)k * 4096 + i * 64 + o];
    }
    if (threadIdx.x < 64) kb3P[threadIdx.x * 64 + i] = kb3[i * 64 + threadIdx.x];
    __syncthreads();
    int ow = threadIdx.x >> 2, kc = (threadIdx.x & 3) * 64;
    int nf = i >> 4, rl = i & 15;
    for (int c = 0; c < 8; ++c) {
        int k0 = kc + c * 8;
        int ks = k0 >> 5, kh = ks >> 2, ks4 = ks & 3, kg = (k0 >> 3) & 3;
        size_t off = (size_t)ow * 16384 + kh * 8192 + ((nf * 4 + ks4) * 64 + kg * 16 + rl) * 8;
        f16x8 v;
#pragma unroll
        for (int jj = 0; jj < 8; ++jj) v[jj] = (f16)T[k0 + jj][ow];
        *(f16x8*)(kW3P + off) = v;
    }
}

// ---------------- fused edge MLP (k1 in LDS, k2 fp16 out) --------------------
__global__ __launch_bounds__(256) void k_edge12(const float* __restrict__ ea, const int* __restrict__ ei,
                                                const int* __restrict__ batch, const float* __restrict__ u,
                                                const float* __restrict__ W1, const float* __restrict__ b1,
                                                const float* __restrict__ W2, const float* __restrict__ b2,
                                                f16* __restrict__ k2) {
    __shared__ float u_s[256];
    __shared__ float ea_s[16][6];
    __shared__ int b_s[16];
    __shared__ float k1_s[16][128];
    int tid = threadIdx.x;
    int e0 = blockIdx.x * 16;
    u_s[tid] = u[tid];
    if (tid < 96) {
        int e = tid / 6, i = tid % 6;
        int eg = e0 + e;
        ea_s[e][i] = (eg < N_EDGES) ? ea[(size_t)eg * 6 + i] : 0.f;
    }
    if (tid < 16) {
        int eg = e0 + tid;
        b_s[tid] = (eg < N_EDGES) ? batch[ei[eg]] : 0;
    }
    __syncthreads();
    int j = tid & 127;
#pragma unroll 1
    for (int p = 0; p < 8; ++p) {
        int e = p * 2 + (tid >> 7);
        float acc = b1[j];
#pragma unroll
        for (int i = 0; i < 6; ++i) acc += ea_s[e][i] * W1[i * 128 + j];
        const float* ur = u_s + b_s[e] * 64;
#pragma unroll
        for (int i = 0; i < 64; ++i) acc += ur[i] * W1[(6 + i) * 128 + j];
        k1_s[e][j] = fmaxf(acc, 0.f);
    }
    __syncthreads();
    float acc2[16];
#pragma unroll
    for (int e = 0; e < 16; ++e) acc2[e] = b2[tid];
    for (int i = 0; i < 128; ++i) {
        float w = W2[(size_t)i * 256 + tid];
#pragma unroll
        for (int e = 0; e < 16; ++e) acc2[e] += k1_s[e][i] * w;
    }
#pragma unroll
    for (int e = 0; e < 16; ++e) {
        int eg = e0 + e;
        k2[(size_t)eg * 256 + tid] = (f16)((eg < N_EDGES) ? fmaxf(acc2[e], 0.f) : 0.f);
    }
}

// ---- fused GEMM + message dot + scatter-mean --------------------------------
// block = 128 edges; waves 2m x 2n; wave = 64 edges (m-rep 4) x 32 cols.
// K split into 2 passes of 128 (A-half in 64 VGPR). Loop: 8-ct group outer,
// pass middle, ct inner; w8 accumulates across passes -> atomics once/group.
// B = 16 KB K-half fragment tiles, dbuf via global_load_lds, 1 barrier/half.
// Cross-wave LDS combine (xw) merges wn-halves before atomicAdd.
__global__ __launch_bounds__(256, 3) void k_fused(const f16* __restrict__ A, const f16* __restrict__ Bf,
                                                  const float* __restrict__ kb3P, const float* __restrict__ h,
                                                  const int* __restrict__ ei, const float* __restrict__ dinv,
                                                  float* __restrict__ agg) {
    __shared__ __align__(16) f16 lB[2][8192];    // 2 x 16 KB
    __shared__ float xw[4][64][9];               // cross-wave combine (padded)
    __shared__ int src_s[128];
    __shared__ int dst_s[128];
    __shared__ float dinv_s[128];
    int tid = threadIdx.x, wave = tid >> 6, lane = tid & 63;
    int wm = wave >> 1, wn = wave & 1;
    int m0 = blockIdx.x * 128;
    int ct0 = blockIdx.y * CT_PER;
    if (tid < 128) {
        int eg = m0 + tid; int s = 0, d = 0; float dv = 0.f;
        if (eg < N_EDGES) { s = ei[eg]; d = ei[N_EDGES + eg]; dv = dinv[d]; }
        src_s[tid] = s; dst_s[tid] = d; dinv_s[tid] = dv;
    }
    // stage first segment: tile (ct0, khalf 0)
    {
        const f16* bp = Bf + (size_t)(ct0 * 2) * 8192;
#pragma unroll
        for (int q = 0; q < 4; ++q)
            gload16(bp + (q * 256 + tid) * 8, &lB[0][(q * 256 + wave * 64) * 8]);
    }
    __syncthreads();   // seg0 drained + src_s visible
    // h rows (pre-scaled by dinv): cols wn*32 + nf*16 + (lane&15)
    float hsr[4][4][2];
#pragma unroll
    for (int mf = 0; mf < 4; ++mf)
#pragma unroll
        for (int jj = 0; jj < 4; ++jj) {
            int el = wm * 64 + mf * 16 + (lane >> 4) * 4 + jj;
            const float* hp = h + (size_t)src_s[el] * 64 + wn * 32 + (lane & 15);
            float dv = dinv_s[el];
#pragma unroll
            for (int nf = 0; nf < 2; ++nf) hsr[mf][jj][nf] = hp[nf * 16] * dv;
        }
    const float* bias_p = kb3P + ct0 * 64 + wn * 32 + (lane & 15);
    const f16* arow = A + (size_t)(m0 + wm * 64 + (lane & 15)) * 256 + (lane >> 4) * 8;
    int cur = 0;
#pragma unroll 1
    for (int gi = 0; gi < NGROUPS; ++gi) {
        float w8[8] = {0.f, 0.f, 0.f, 0.f, 0.f, 0.f, 0.f, 0.f};
#pragma unroll
        for (int p = 0; p < 2; ++p) {
            // A fragments for k-half p (reloaded per group-pass; L1/L2-resident)
            f16x8 a[4][4];
#pragma unroll
            for (int mf = 0; mf < 4; ++mf)
#pragma unroll
                for (int ks4 = 0; ks4 < 4; ++ks4)
                    a[mf][ks4] = *(const f16x8*)(arow + (size_t)mf * 16 * 256 + p * 128 + ks4 * 32);
#pragma unroll
            for (int q8 = 0; q8 < 8; ++q8) {
                int ctl = gi * 8 + q8;
                // prefetch next segment (tile ids: (ct0+ctl)*2+p ordering within group)
                bool doPf = true; int nt = 0;
                if (q8 < 7)      nt = (ct0 + ctl + 1) * 2 + p;
                else if (p == 0) nt = (ct0 + gi * 8) * 2 + 1;
                else { nt = (ct0 + (gi + 1) * 8) * 2; doPf = (gi + 1 < NGROUPS); }
                if (doPf) {
                    const f16* bp = Bf + (size_t)nt * 8192;
#pragma unroll
                    for (int q = 0; q < 4; ++q)
                        gload16(bp + (q * 256 + tid) * 8, &lB[cur ^ 1][(q * 256 + wave * 64) * 8]);
                }
                // acc init: bias only in pass 0 (once per (e,o))
                f32x4 acc[4][2];
#pragma unroll
                for (int nf = 0; nf < 2; ++nf) {
                    float bv = (p == 0) ? bias_p[ctl * 64 + nf * 16] : 0.f;
#pragma unroll
                    for (int mf = 0; mf < 4; ++mf) acc[mf][nf] = {bv, bv, bv, bv};
                }
                const f16* lb = lB[cur];
#pragma unroll
                for (int ks4 = 0; ks4 < 4; ++ks4) {
                    f16x8 bf[2];
#pragma unroll
                    for (int nf = 0; nf < 2; ++nf)
                        bf[nf] = *(const f16x8*)(lb + ((wn * 2 + nf) * 4 + ks4) * 512 + lane * 8);
#pragma unroll
                    for (int mf = 0; mf < 4; ++mf)
#pragma unroll
                        for (int nf = 0; nf < 2; ++nf)
                            acc[mf][nf] = __builtin_amdgcn_mfma_f32_16x16x32_f16(a[mf][ks4], bf[nf], acc[mf][nf], 0, 0, 0);
                }
                // per-lane partials over this wave's 32 cols
                float v[16];
#pragma unroll
                for (int mf = 0; mf < 4; ++mf)
#pragma unroll
                    for (int jj = 0; jj < 4; ++jj)
                        v[mf * 4 + jj] = acc[mf][0][jj] * hsr[mf][jj][0] + acc[mf][1][jj] * hsr[mf][jj][1];
                // 16-value fold tree (15 shfl): lane ends with v[lane&15] 16-lane-summed
                float t[8];
#pragma unroll
                for (int i = 0; i < 8; ++i) t[i] = foldp(v[2 * i], v[2 * i + 1], 1, lane);
                float uu[4];
#pragma unroll
                for (int i = 0; i < 4; ++i) uu[i] = foldp(t[2 * i], t[2 * i + 1], 2, lane);
                float ss[2];
#pragma unroll
                for (int i = 0; i < 2; ++i) ss[i] = foldp(uu[2 * i], uu[2 * i + 1], 4, lane);
                w8[q8] += foldp(ss[0], ss[1], 8, lane);
                cur ^= 1;
                __syncthreads();   // drains prefetch; WAR on consumed buffer
            }
        }
        // cross-wave combine + flush (atomics once per group, full K both wn)
#pragma unroll
        for (int q = 0; q < 8; ++q) xw[wave][lane][q] = w8[q];
        __syncthreads();
        {
            int mf = (lane >> 2) & 3, jj = lane & 3;
            int el = wm * 64 + mf * 16 + (lane >> 4) * 4 + jj;
            float* ap2 = agg + (size_t)dst_s[el] * 64 + ct0 + gi * 8 + wn * 4;
#pragma unroll
            for (int qq = 0; qq < 4; ++qq) {
                int q = wn * 4 + qq;
                atomicAdd(ap2 + qq, xw[wm * 2][lane][q] + xw[wm * 2 + 1][lane][q]);
            }
        }
        // next xw write is 16 barriers away -> no WAR barrier needed
    }
}

// ---------------- node update: h' = relu(agg + h@root + bias) ----------------
__global__ void k_update(const float* __restrict__ agg, const float* __restrict__ h,
                         const float* __restrict__ root, const float* __restrict__ bias,
                         float* __restrict__ hn) {
    __shared__ float t[4][64];
    int g = threadIdx.x >> 6, j = threadIdx.x & 63;
    int node = blockIdx.x * 4 + g;
    t[g][j] = h[node * 64 + j];
    __syncthreads();
    float acc = agg[node * 64 + j] + bias[j];
#pragma unroll
    for (int i = 0; i < 64; ++i) acc += t[g][i] * root[i * 64 + j];
    hn[node * 64 + j] = fmaxf(acc, 0.f);
}

// ---------------- output head ------------------------------------------------
__global__ void k_out(const float* __restrict__ h, const float* __restrict__ oW,
                      const float* __restrict__ ob, float* __restrict__ out) {
    int wg = (blockIdx.x * 256 + threadIdx.x) >> 6;
    int lane = threadIdx.x & 63;
    if (wg >= N_NODES) return;
    float p = h[wg * 64 + lane] * oW[lane];
#pragma unroll
    for (int s = 32; s > 0; s >>= 1) p += __shfl_xor(p, s);
    if (lane == 0) out[wg] = p + ob[0];
}

__global__ void k_sentinel(float* out) { out[0] = 1e30f; }

extern "C" void kernel_launch(void* const* d_in, const int* in_sizes, int n_in,
                              void* d_out, int out_size, void* d_ws, size_t ws_size,
                              hipStream_t stream) {
    const float* x          = (const float*)d_in[0];
    const float* edge_attr  = (const float*)d_in[1];
    const float* conditions = (const float*)d_in[2];
    const float* scale      = (const float*)d_in[3];
    const int*   edge_index = (const int*)d_in[4];
    const int*   batch      = (const int*)d_in[5];
    const float* nW1 = (const float*)d_in[6];  const float* nb1 = (const float*)d_in[7];
    const float* nW2 = (const float*)d_in[8];  const float* nb2 = (const float*)d_in[9];
    const float* cW1 = (const float*)d_in[10]; const float* cb1 = (const float*)d_in[11];
    const float* cW2 = (const float*)d_in[12]; const float* cb2 = (const float*)d_in[13];
    const float* kW1 = (const float*)d_in[14]; const float* kb1 = (const float*)d_in[15];
    const float* kW2 = (const float*)d_in[16]; const float* kb2 = (const float*)d_in[17];
    const float* kW3 = (const float*)d_in[18]; const float* kb3 = (const float*)d_in[19];
    const float* root = (const float*)d_in[20]; const float* conv_bias = (const float*)d_in[21];
    const float* oW  = (const float*)d_in[22]; const float* ob  = (const float*)d_in[23];
    float* out = (float*)d_out;

    char* ws = (char*)d_ws;
    size_t off = 0;
    auto alloc = [&](size_t bytes) -> char* {
        char* p = ws + off;
        off += (bytes + 255) & ~(size_t)255;
        return p;
    };
    float* h_a  = (float*)alloc((size_t)N_NODES * 64 * 4);
    float* h_b  = (float*)alloc((size_t)N_NODES * 64 * 4);
    float* agg  = (float*)alloc((size_t)N_NODES * 64 * 4);
    float* u    = (float*)alloc(256 * 4);
    float* deg  = (float*)alloc((size_t)N_NODES * 4);
    f16*   k2   = (f16*)alloc((size_t)EPAD * 256 * 2);
    f16*   kW3P = (f16*)alloc((size_t)4096 * 256 * 2);
    float* kb3P = (float*)alloc(4096 * 4);
    // total ~43 MB

    if (off > ws_size) {  // workspace too small: distinct sentinel
        k_sentinel<<<1, 1, 0, stream>>>(out);
        return;
    }

    hipMemsetAsync(deg, 0, (size_t)N_NODES * 4, stream);
    k_node_enc<<<2500, 256, 0, stream>>>(x, nW1, nb1, nW2, nb2, h_a);
    k_cond_enc<<<1, 256, 0, stream>>>(conditions, scale, cW1, cb1, cW2, cb2, u, out + N_NODES);
    k_deg<<<(N_EDGES + 255) / 256, 256, 0, stream>>>(edge_index + N_EDGES, deg);
    k_deg_inv<<<(N_NODES + 255) / 256, 256, 0, stream>>>(deg);
    k_permute<<<64, 256, 0, stream>>>(kW3, kb3, kW3P, kb3P);
    k_edge12<<<EPAD / 16, 256, 0, stream>>>(edge_attr, edge_index, batch, u, kW1, kb1, kW2, kb2, k2);

    float* hc = h_a; float* hn = h_b;
    for (int l = 0; l < 3; ++l) {
        hipMemsetAsync(agg, 0, (size_t)N_NODES * 64 * 4, stream);
        k_fused<<<dim3(EPAD / 128, CSPLIT), 256, 0, stream>>>(k2, kW3P, kb3P, hc, edge_index, deg, agg);
        k_update<<<2500, 256, 0, stream>>>(agg, hc, root, conv_bias, hn);
        float* tmp = hc; hc = hn; hn = tmp;
    }
    k_out<<<2500, 256, 0, stream>>>(hc, oW, ob, out);
}

// Round 12
// 1446.763 us; speedup vs baseline: 2.5725x; 2.5725x over previous
//
#include <hip/hip_runtime.h>
#include <hip/hip_fp16.h>

#define N_NODES 10000
#define N_EDGES 60000
#define EPAD    60032   // multiple of 128
#define CSPLIT  2
#define CT_PER  32      // 64 / CSPLIT
#define NGROUPS 4       // CT_PER / 8

typedef _Float16 f16;
typedef f16 f16x8 __attribute__((ext_vector_type(8)));
typedef float f32x4 __attribute__((ext_vector_type(4)));

__device__ __forceinline__ void gload16(const void* g, void* l) {
    __builtin_amdgcn_global_load_lds((const __attribute__((address_space(1))) unsigned int*)g,
                                     (__attribute__((address_space(3))) unsigned int*)l, 16, 0, 0);
}

// select-then-pair-sum: bit-clear lanes end with a_l + a_{l^m}; bit-set with b_l + b_{l^m}
__device__ __forceinline__ float foldp(float a, float b, int m, int lane) {
    float x = (lane & m) ? b : a;
    float y = (lane & m) ? a : b;
    return x + __shfl_xor(y, m);
}

// ---------------- node encoder: h = relu(x@nW1+nb1)@nW2+nb2 ----------------
__global__ void k_node_enc(const float* __restrict__ x, const float* __restrict__ W1,
                           const float* __restrict__ b1, const float* __restrict__ W2,
                           const float* __restrict__ b2, float* __restrict__ h) {
    __shared__ float t[4][64];
    int g = threadIdx.x >> 6, j = threadIdx.x & 63;
    int node = blockIdx.x * 4 + g;
    float acc = b1[j];
#pragma unroll
    for (int i = 0; i < 6; ++i) acc += x[node * 6 + i] * W1[i * 64 + j];
    t[g][j] = fmaxf(acc, 0.f);
    __syncthreads();
    float acc2 = b2[j];
#pragma unroll
    for (int i = 0; i < 64; ++i) acc2 += t[g][i] * W2[i * 64 + j];
    h[node * 64 + j] = acc2;
}

// ---------------- condition encoder -----------------------------------------
__global__ void k_cond_enc(const float* __restrict__ cond, const float* __restrict__ scl,
                           const float* __restrict__ W1, const float* __restrict__ b1,
                           const float* __restrict__ W2, const float* __restrict__ b2,
                           float* __restrict__ u, float* __restrict__ out_u) {
    __shared__ float t[4][64];
    __shared__ float cat[4][14];
    int g = threadIdx.x >> 6, j = threadIdx.x & 63;
    if (threadIdx.x < 56) {
        int b = threadIdx.x / 14, i = threadIdx.x % 14;
        cat[b][i] = (i < 10) ? cond[b * 10 + i] : scl[b * 4 + (i - 10)];
    }
    __syncthreads();
    float acc = b1[j];
#pragma unroll
    for (int i = 0; i < 14; ++i) acc += cat[g][i] * W1[i * 64 + j];
    t[g][j] = fmaxf(acc, 0.f);
    __syncthreads();
    float acc2 = b2[j];
#pragma unroll
    for (int i = 0; i < 64; ++i) acc2 += t[g][i] * W2[i * 64 + j];
    u[g * 64 + j] = acc2;
    out_u[g * 64 + j] = acc2;
}

// ---------------- degree -----------------------------------------------------
__global__ void k_deg(const int* __restrict__ dst, float* __restrict__ deg) {
    int e = blockIdx.x * 256 + threadIdx.x;
    if (e < N_EDGES) atomicAdd(&deg[dst[e]], 1.0f);
}
__global__ void k_deg_inv(float* __restrict__ deg) {
    int n = blockIdx.x * 256 + threadIdx.x;
    if (n < N_NODES) deg[n] = 1.0f / fmaxf(deg[n], 1.0f);
}

// ------- permute kW3 into FRAGMENT-ORDERED K-HALF tiles + kb3P ---------------
// tile t = ct*2 + kh (16 KB each): offset = t*8192 + ((nf*4+ks4)*64 + kg*16 + rl)*8
// element j there = kW3[k][i*64+ct] with i=nf*16+rl, k=kh*128 + ks4*32 + kg*8 + j
__global__ void k_permute(const float* __restrict__ kW3, const float* __restrict__ kb3,
                          f16* __restrict__ kW3P, float* __restrict__ kb3P) {
    __shared__ float T[256][65];
    int i = blockIdx.x;                 // 0..63 (inner input index)
    int o = threadIdx.x & 63, kq = threadIdx.x >> 6;
    for (int kk = 0; kk < 64; ++kk) {
        int k = kk * 4 + kq;
        T[k][o] = kW3[(size_t)k * 4096 + i * 64 + o];
    }
    if (threadIdx.x < 64) kb3P[threadIdx.x * 64 + i] = kb3[i * 64 + threadIdx.x];
    __syncthreads();
    int ow = threadIdx.x >> 2, kc = (threadIdx.x & 3) * 64;
    int nf = i >> 4, rl = i & 15;
    for (int c = 0; c < 8; ++c) {
        int k0 = kc + c * 8;
        int ks = k0 >> 5, kh = ks >> 2, ks4 = ks & 3, kg = (k0 >> 3) & 3;
        size_t off = (size_t)ow * 16384 + kh * 8192 + ((nf * 4 + ks4) * 64 + kg * 16 + rl) * 8;
        f16x8 v;
#pragma unroll
        for (int jj = 0; jj < 8; ++jj) v[jj] = (f16)T[k0 + jj][ow];
        *(f16x8*)(kW3P + off) = v;
    }
}

// ---------------- fused edge MLP (k1 in LDS, k2 fp16 out) --------------------
__global__ __launch_bounds__(256) void k_edge12(const float* __restrict__ ea, const int* __restrict__ ei,
                                                const int* __restrict__ batch, const float* __restrict__ u,
                                                const float* __restrict__ W1, const float* __restrict__ b1,
                                                const float* __restrict__ W2, const float* __restrict__ b2,
                                                f16* __restrict__ k2) {
    __shared__ float u_s[256];
    __shared__ float ea_s[16][6];
    __shared__ int b_s[16];
    __shared__ float k1_s[16][128];
    int tid = threadIdx.x;
    int e0 = blockIdx.x * 16;
    u_s[tid] = u[tid];
    if (tid < 96) {
        int e = tid / 6, i = tid % 6;
        int eg = e0 + e;
        ea_s[e][i] = (eg < N_EDGES) ? ea[(size_t)eg * 6 + i] : 0.f;
    }
    if (tid < 16) {
        int eg = e0 + tid;
        b_s[tid] = (eg < N_EDGES) ? batch[ei[eg]] : 0;
    }
    __syncthreads();
    int j = tid & 127;
#pragma unroll 1
    for (int p = 0; p < 8; ++p) {
        int e = p * 2 + (tid >> 7);
        float acc = b1[j];
#pragma unroll
        for (int i = 0; i < 6; ++i) acc += ea_s[e][i] * W1[i * 128 + j];
        const float* ur = u_s + b_s[e] * 64;
#pragma unroll
        for (int i = 0; i < 64; ++i) acc += ur[i] * W1[(6 + i) * 128 + j];
        k1_s[e][j] = fmaxf(acc, 0.f);
    }
    __syncthreads();
    float acc2[16];
#pragma unroll
    for (int e = 0; e < 16; ++e) acc2[e] = b2[tid];
    for (int i = 0; i < 128; ++i) {
        float w = W2[(size_t)i * 256 + tid];
#pragma unroll
        for (int e = 0; e < 16; ++e) acc2[e] += k1_s[e][i] * w;
    }
#pragma unroll
    for (int e = 0; e < 16; ++e) {
        int eg = e0 + e;
        k2[(size_t)eg * 256 + tid] = (f16)((eg < N_EDGES) ? fmaxf(acc2[e], 0.f) : 0.f);
    }
}

// ---- fused GEMM + message dot + scatter-mean --------------------------------
// block = 128 edges; waves 2m x 2n; wave = 64 edges (m-rep 4) x 32 cols.
// K split into 2 passes of 128 (A-half in 64 VGPR). Loop: 8-ct group outer,
// pass middle, ct inner; w8 accumulates across passes -> atomics once/group.
// B = 16 KB K-half fragment tiles, dbuf via global_load_lds, 1 barrier/half.
// Cross-wave LDS combine (xw) merges wn-halves before atomicAdd.
// NOTE: NO second launch_bounds arg — on this toolchain it caps VGPR at
// 512/(2N) (rounds 9/11: 64 and 84 VGPR -> GB-scale scratch spills).
__global__ __launch_bounds__(256) void k_fused(const f16* __restrict__ A, const f16* __restrict__ Bf,
                                               const float* __restrict__ kb3P, const float* __restrict__ h,
                                               const int* __restrict__ ei, const float* __restrict__ dinv,
                                               float* __restrict__ agg) {
    __shared__ __align__(16) f16 lB[2][8192];    // 2 x 16 KB
    __shared__ float xw[4][64][9];               // cross-wave combine (padded)
    __shared__ int src_s[128];
    __shared__ int dst_s[128];
    __shared__ float dinv_s[128];
    int tid = threadIdx.x, wave = tid >> 6, lane = tid & 63;
    int wm = wave >> 1, wn = wave & 1;
    int m0 = blockIdx.x * 128;
    int ct0 = blockIdx.y * CT_PER;
    if (tid < 128) {
        int eg = m0 + tid; int s = 0, d = 0; float dv = 0.f;
        if (eg < N_EDGES) { s = ei[eg]; d = ei[N_EDGES + eg]; dv = dinv[d]; }
        src_s[tid] = s; dst_s[tid] = d; dinv_s[tid] = dv;
    }
    // stage first segment: tile (ct0, khalf 0)
    {
        const f16* bp = Bf + (size_t)(ct0 * 2) * 8192;
#pragma unroll
        for (int q = 0; q < 4; ++q)
            gload16(bp + (q * 256 + tid) * 8, &lB[0][(q * 256 + wave * 64) * 8]);
    }
    __syncthreads();   // seg0 drained + src_s visible
    // h rows (pre-scaled by dinv): cols wn*32 + nf*16 + (lane&15)
    float hsr[4][4][2];
#pragma unroll
    for (int mf = 0; mf < 4; ++mf)
#pragma unroll
        for (int jj = 0; jj < 4; ++jj) {
            int el = wm * 64 + mf * 16 + (lane >> 4) * 4 + jj;
            const float* hp = h + (size_t)src_s[el] * 64 + wn * 32 + (lane & 15);
            float dv = dinv_s[el];
#pragma unroll
            for (int nf = 0; nf < 2; ++nf) hsr[mf][jj][nf] = hp[nf * 16] * dv;
        }
    const float* bias_p = kb3P + ct0 * 64 + wn * 32 + (lane & 15);
    const f16* arow = A + (size_t)(m0 + wm * 64 + (lane & 15)) * 256 + (lane >> 4) * 8;
    int cur = 0;
#pragma unroll 1
    for (int gi = 0; gi < NGROUPS; ++gi) {
        float w8[8] = {0.f, 0.f, 0.f, 0.f, 0.f, 0.f, 0.f, 0.f};
#pragma unroll
        for (int p = 0; p < 2; ++p) {
            // A fragments for k-half p (reloaded per group-pass; L1/L2-resident)
            f16x8 a[4][4];
#pragma unroll
            for (int mf = 0; mf < 4; ++mf)
#pragma unroll
                for (int ks4 = 0; ks4 < 4; ++ks4)
                    a[mf][ks4] = *(const f16x8*)(arow + (size_t)mf * 16 * 256 + p * 128 + ks4 * 32);
#pragma unroll
            for (int q8 = 0; q8 < 8; ++q8) {
                int ctl = gi * 8 + q8;
                // prefetch next segment (tile ids: (ct0+ctl)*2+p ordering within group)
                bool doPf = true; int nt = 0;
                if (q8 < 7)      nt = (ct0 + ctl + 1) * 2 + p;
                else if (p == 0) nt = (ct0 + gi * 8) * 2 + 1;
                else { nt = (ct0 + (gi + 1) * 8) * 2; doPf = (gi + 1 < NGROUPS); }
                if (doPf) {
                    const f16* bp = Bf + (size_t)nt * 8192;
#pragma unroll
                    for (int q = 0; q < 4; ++q)
                        gload16(bp + (q * 256 + tid) * 8, &lB[cur ^ 1][(q * 256 + wave * 64) * 8]);
                }
                // acc init: bias only in pass 0 (once per (e,o))
                f32x4 acc[4][2];
#pragma unroll
                for (int nf = 0; nf < 2; ++nf) {
                    float bv = (p == 0) ? bias_p[ctl * 64 + nf * 16] : 0.f;
#pragma unroll
                    for (int mf = 0; mf < 4; ++mf) acc[mf][nf] = {bv, bv, bv, bv};
                }
                const f16* lb = lB[cur];
#pragma unroll
                for (int ks4 = 0; ks4 < 4; ++ks4) {
                    f16x8 bf[2];
#pragma unroll
                    for (int nf = 0; nf < 2; ++nf)
                        bf[nf] = *(const f16x8*)(lb + ((wn * 2 + nf) * 4 + ks4) * 512 + lane * 8);
#pragma unroll
                    for (int mf = 0; mf < 4; ++mf)
#pragma unroll
                        for (int nf = 0; nf < 2; ++nf)
                            acc[mf][nf] = __builtin_amdgcn_mfma_f32_16x16x32_f16(a[mf][ks4], bf[nf], acc[mf][nf], 0, 0, 0);
                }
                // per-lane partials over this wave's 32 cols
                float v[16];
#pragma unroll
                for (int mf = 0; mf < 4; ++mf)
#pragma unroll
                    for (int jj = 0; jj < 4; ++jj)
                        v[mf * 4 + jj] = acc[mf][0][jj] * hsr[mf][jj][0] + acc[mf][1][jj] * hsr[mf][jj][1];
                // 16-value fold tree (15 shfl): lane ends with v[lane&15] 16-lane-summed
                float t[8];
#pragma unroll
                for (int i = 0; i < 8; ++i) t[i] = foldp(v[2 * i], v[2 * i + 1], 1, lane);
                float uu[4];
#pragma unroll
                for (int i = 0; i < 4; ++i) uu[i] = foldp(t[2 * i], t[2 * i + 1], 2, lane);
                float ss[2];
#pragma unroll
                for (int i = 0; i < 2; ++i) ss[i] = foldp(uu[2 * i], uu[2 * i + 1], 4, lane);
                w8[q8] += foldp(ss[0], ss[1], 8, lane);
                cur ^= 1;
                __syncthreads();   // drains prefetch; WAR on consumed buffer
            }
        }
        // cross-wave combine + flush (atomics once per group, full K both wn)
#pragma unroll
        for (int q = 0; q < 8; ++q) xw[wave][lane][q] = w8[q];
        __syncthreads();
        {
            int mf = (lane >> 2) & 3, jj = lane & 3;
            int el = wm * 64 + mf * 16 + (lane >> 4) * 4 + jj;
            float* ap2 = agg + (size_t)dst_s[el] * 64 + ct0 + gi * 8 + wn * 4;
#pragma unroll
            for (int qq = 0; qq < 4; ++qq) {
                int q = wn * 4 + qq;
                atomicAdd(ap2 + qq, xw[wm * 2][lane][q] + xw[wm * 2 + 1][lane][q]);
            }
        }
        // next xw write is 16 barriers away -> no WAR barrier needed
    }
}

// ---------------- node update: h' = relu(agg + h@root + bias) ----------------
__global__ void k_update(const float* __restrict__ agg, const float* __restrict__ h,
                         const float* __restrict__ root, const float* __restrict__ bias,
                         float* __restrict__ hn) {
    __shared__ float t[4][64];
    int g = threadIdx.x >> 6, j = threadIdx.x & 63;
    int node = blockIdx.x * 4 + g;
    t[g][j] = h[node * 64 + j];
    __syncthreads();
    float acc = agg[node * 64 + j] + bias[j];
#pragma unroll
    for (int i = 0; i < 64; ++i) acc += t[g][i] * root[i * 64 + j];
    hn[node * 64 + j] = fmaxf(acc, 0.f);
}

// ---------------- output head ------------------------------------------------
__global__ void k_out(const float* __restrict__ h, const float* __restrict__ oW,
                      const float* __restrict__ ob, float* __restrict__ out) {
    int wg = (blockIdx.x * 256 + threadIdx.x) >> 6;
    int lane = threadIdx.x & 63;
    if (wg >= N_NODES) return;
    float p = h[wg * 64 + lane] * oW[lane];
#pragma unroll
    for (int s = 32; s > 0; s >>= 1) p += __shfl_xor(p, s);
    if (lane == 0) out[wg] = p + ob[0];
}

__global__ void k_sentinel(float* out) { out[0] = 1e30f; }

extern "C" void kernel_launch(void* const* d_in, const int* in_sizes, int n_in,
                              void* d_out, int out_size, void* d_ws, size_t ws_size,
                              hipStream_t stream) {
    const float* x          = (const float*)d_in[0];
    const float* edge_attr  = (const float*)d_in[1];
    const float* conditions = (const float*)d_in[2];
    const float* scale      = (const float*)d_in[3];
    const int*   edge_index = (const int*)d_in[4];
    const int*   batch      = (const int*)d_in[5];
    const float* nW1 = (const float*)d_in[6];  const float* nb1 = (const float*)d_in[7];
    const float* nW2 = (const float*)d_in[8];  const float* nb2 = (const float*)d_in[9];
    const float* cW1 = (const float*)d_in[10]; const float* cb1 = (const float*)d_in[11];
    const float* cW2 = (const float*)d_in[12]; const float* cb2 = (const float*)d_in[13];
    const float* kW1 = (const float*)d_in[14]; const float* kb1 = (const float*)d_in[15];
    const float* kW2 = (const float*)d_in[16]; const float* kb2 = (const float*)d_in[17];
    const float* kW3 = (const float*)d_in[18]; const float* kb3 = (const float*)d_in[19];
    const float* root = (const float*)d_in[20]; const float* conv_bias = (const float*)d_in[21];
    const float* oW  = (const float*)d_in[22]; const float* ob  = (const float*)d_in[23];
    float* out = (float*)d_out;

    char* ws = (char*)d_ws;
    size_t off = 0;
    auto alloc = [&](size_t bytes) -> char* {
        char* p = ws + off;
        off += (bytes + 255) & ~(size_t)255;
        return p;
    };
    float* h_a  = (float*)alloc((size_t)N_NODES * 64 * 4);
    float* h_b  = (float*)alloc((size_t)N_NODES * 64 * 4);
    float* agg  = (float*)alloc((size_t)N_NODES * 64 * 4);
    float* u    = (float*)alloc(256 * 4);
    float* deg  = (float*)alloc((size_t)N_NODES * 4);
    f16*   k2   = (f16*)alloc((size_t)EPAD * 256 * 2);
    f16*   kW3P = (f16*)alloc((size_t)4096 * 256 * 2);
    float* kb3P = (float*)alloc(4096 * 4);
    // total ~43 MB

    if (off > ws_size) {  // workspace too small: distinct sentinel
        k_sentinel<<<1, 1, 0, stream>>>(out);
        return;
    }

    hipMemsetAsync(deg, 0, (size_t)N_NODES * 4, stream);
    k_node_enc<<<2500, 256, 0, stream>>>(x, nW1, nb1, nW2, nb2, h_a);
    k_cond_enc<<<1, 256, 0, stream>>>(conditions, scale, cW1, cb1, cW2, cb2, u, out + N_NODES);
    k_deg<<<(N_EDGES + 255) / 256, 256, 0, stream>>>(edge_index + N_EDGES, deg);
    k_deg_inv<<<(N_NODES + 255) / 256, 256, 0, stream>>>(deg);
    k_permute<<<64, 256, 0, stream>>>(kW3, kb3, kW3P, kb3P);
    k_edge12<<<EPAD / 16, 256, 0, stream>>>(edge_attr, edge_index, batch, u, kW1, kb1, kW2, kb2, k2);

    float* hc = h_a; float* hn = h_b;
    for (int l = 0; l < 3; ++l) {
        hipMemsetAsync(agg, 0, (size_t)N_NODES * 64 * 4, stream);
        k_fused<<<dim3(EPAD / 128, CSPLIT), 256, 0, stream>>>(k2, kW3P, kb3P, hc, edge_index, deg, agg);
        k_update<<<2500, 256, 0, stream>>>(agg, hc, root, conv_bias, hn);
        float* tmp = hc; hc = hn; hn = tmp;
    }
    k_out<<<2500, 256, 0, stream>>>(hc, oW, ob, out);
}

// Round 13
// 1237.410 us; speedup vs baseline: 3.0077x; 1.1692x over previous
//
#include <hip/hip_runtime.h>
#include <hip/hip_fp16.h>

#define N_NODES 10000
#define NPAD    10016   // multiple of 32
#define N_EDGES 60000
#define EPAD    60032

typedef _Float16 f16;
typedef f16 f16x8 __attribute__((ext_vector_type(8)));
typedef f16 f16x2 __attribute__((ext_vector_type(2)));
typedef float f32x4 __attribute__((ext_vector_type(4)));

#define SV2(v, j) __builtin_shufflevector(v, v, 2 * (j), 2 * (j) + 1)

#if __has_builtin(__builtin_amdgcn_fdot2)
__device__ __forceinline__ float FDOT2(f16x2 a, f16x2 b, float c) {
    return __builtin_amdgcn_fdot2(a, b, c, false);
}
#else
__device__ __forceinline__ float FDOT2(f16x2 a, f16x2 b, float c) {
    return c + (float)a[0] * (float)b[0] + (float)a[1] * (float)b[1];
}
#endif

// ---------------- node encoder: h = relu(x@nW1+nb1)@nW2+nb2 (+f16 copy) ----
__global__ void k_node_enc(const float* __restrict__ x, const float* __restrict__ W1,
                           const float* __restrict__ b1, const float* __restrict__ W2,
                           const float* __restrict__ b2, float* __restrict__ h,
                           f16* __restrict__ h16) {
    __shared__ float t[4][64];
    int g = threadIdx.x >> 6, j = threadIdx.x & 63;
    int node = blockIdx.x * 4 + g;
    float acc = b1[j];
#pragma unroll
    for (int i = 0; i < 6; ++i) acc += x[node * 6 + i] * W1[i * 64 + j];
    t[g][j] = fmaxf(acc, 0.f);
    __syncthreads();
    float acc2 = b2[j];
#pragma unroll
    for (int i = 0; i < 64; ++i) acc2 += t[g][i] * W2[i * 64 + j];
    h[node * 64 + j] = acc2;
    h16[node * 64 + j] = (f16)acc2;
}

// ---------------- condition encoder -----------------------------------------
__global__ void k_cond_enc(const float* __restrict__ cond, const float* __restrict__ scl,
                           const float* __restrict__ W1, const float* __restrict__ b1,
                           const float* __restrict__ W2, const float* __restrict__ b2,
                           float* __restrict__ u, float* __restrict__ out_u) {
    __shared__ float t[4][64];
    __shared__ float cat[4][14];
    int g = threadIdx.x >> 6, j = threadIdx.x & 63;
    if (threadIdx.x < 56) {
        int b = threadIdx.x / 14, i = threadIdx.x % 14;
        cat[b][i] = (i < 10) ? cond[b * 10 + i] : scl[b * 4 + (i - 10)];
    }
    __syncthreads();
    float acc = b1[j];
#pragma unroll
    for (int i = 0; i < 14; ++i) acc += cat[g][i] * W1[i * 64 + j];
    t[g][j] = fmaxf(acc, 0.f);
    __syncthreads();
    float acc2 = b2[j];
#pragma unroll
    for (int i = 0; i < 64; ++i) acc2 += t[g][i] * W2[i * 64 + j];
    u[g * 64 + j] = acc2;
    out_u[g * 64 + j] = acc2;
}

// ---------------- degree -----------------------------------------------------
__global__ void k_deg(const int* __restrict__ dst, float* __restrict__ deg) {
    int e = blockIdx.x * 256 + threadIdx.x;
    if (e < N_EDGES) atomicAdd(&deg[dst[e]], 1.0f);
}
__global__ void k_deg_inv(float* __restrict__ deg) {
    int n = blockIdx.x * 256 + threadIdx.x;
    if (n < N_NODES) deg[n] = 1.0f / fmaxf(deg[n], 1.0f);
}

// ---------------- src-CSR build ----------------------------------------------
__global__ void k_csr_count(const int* __restrict__ src, int* __restrict__ cnt) {
    int e = blockIdx.x * 256 + threadIdx.x;
    if (e < N_EDGES) atomicAdd(&cnt[src[e]], 1);
}
__global__ void k_csr_scan(const int* __restrict__ cnt, int* __restrict__ srcPtr,
                           int* __restrict__ cursor) {
    __shared__ int part[256];
    int t = threadIdx.x;
    int base = t * 40;
    int s = 0;
#pragma unroll 1
    for (int i = 0; i < 40; ++i) { int idx = base + i; if (idx < NPAD) s += cnt[idx]; }
    part[t] = s;
    __syncthreads();
    if (t == 0) {
        int run = 0;
        for (int i = 0; i < 256; ++i) { int v = part[i]; part[i] = run; run += v; }
    }
    __syncthreads();
    int run = part[t];
#pragma unroll 1
    for (int i = 0; i < 40; ++i) {
        int idx = base + i;
        if (idx <= NPAD) {
            srcPtr[idx] = run; cursor[idx] = run;
            if (idx < NPAD) run += cnt[idx];
        }
    }
}
__global__ void k_csr_fill(const int* __restrict__ src, int* __restrict__ cursor,
                           int* __restrict__ srcIdx) {
    int e = blockIdx.x * 256 + threadIdx.x;
    if (e < N_EDGES) { int p = atomicAdd(&cursor[src[e]], 1); srcIdx[p] = e; }
}

// ------- permute kW3 -> Mp2[c][i] = kW3[k][i*64+o], c = o*256+k, f16 ---------
__global__ void k_mp2(const float* __restrict__ kW3, f16* __restrict__ Mp2) {
    int k = threadIdx.x, o = blockIdx.x, ib = blockIdx.y;
#pragma unroll
    for (int j = 0; j < 8; ++j) {
        int i = ib * 8 + j;
        Mp2[((size_t)o * 256 + k) * 64 + i] = (f16)kW3[(size_t)k * 4096 + i * 64 + o];
    }
}

// ---------------- hb[n][o] = sum_i h[n][i]*kb3[i*64+o] (bias term) ----------
__global__ void k_hb(const float* __restrict__ h, const float* __restrict__ kb3,
                     float* __restrict__ hb) {
    __shared__ float t[4][64];
    int g = threadIdx.x >> 6, j = threadIdx.x & 63;
    int node = blockIdx.x * 4 + g;
    t[g][j] = h[node * 64 + j];
    __syncthreads();
    float acc = 0.f;
#pragma unroll
    for (int i = 0; i < 64; ++i) acc += t[g][i] * kb3[i * 64 + j];
    hb[node * 64 + j] = acc;
}

// ---------------- fused edge MLP (k1 in LDS, k2 fp16 out) --------------------
__global__ __launch_bounds__(256) void k_edge12(const float* __restrict__ ea, const int* __restrict__ ei,
                                                const int* __restrict__ batch, const float* __restrict__ u,
                                                const float* __restrict__ W1, const float* __restrict__ b1,
                                                const float* __restrict__ W2, const float* __restrict__ b2,
                                                f16* __restrict__ k2) {
    __shared__ float u_s[256];
    __shared__ float ea_s[16][6];
    __shared__ int b_s[16];
    __shared__ float k1_s[16][128];
    int tid = threadIdx.x;
    int e0 = blockIdx.x * 16;
    u_s[tid] = u[tid];
    if (tid < 96) {
        int e = tid / 6, i = tid % 6;
        int eg = e0 + e;
        ea_s[e][i] = (eg < N_EDGES) ? ea[(size_t)eg * 6 + i] : 0.f;
    }
    if (tid < 16) {
        int eg = e0 + tid;
        b_s[tid] = (eg < N_EDGES) ? batch[ei[eg]] : 0;
    }
    __syncthreads();
    int j = tid & 127;
#pragma unroll 1
    for (int p = 0; p < 8; ++p) {
        int e = p * 2 + (tid >> 7);
        float acc = b1[j];
#pragma unroll
        for (int i = 0; i < 6; ++i) acc += ea_s[e][i] * W1[i * 128 + j];
        const float* ur = u_s + b_s[e] * 64;
#pragma unroll
        for (int i = 0; i < 64; ++i) acc += ur[i] * W1[(6 + i) * 128 + j];
        k1_s[e][j] = fmaxf(acc, 0.f);
    }
    __syncthreads();
    float acc2[16];
#pragma unroll
    for (int e = 0; e < 16; ++e) acc2[e] = b2[tid];
    for (int i = 0; i < 128; ++i) {
        float w = W2[(size_t)i * 256 + tid];
#pragma unroll
        for (int e = 0; e < 16; ++e) acc2[e] += k1_s[e][i] * w;
    }
#pragma unroll
    for (int e = 0; e < 16; ++e) {
        int eg = e0 + e;
        k2[(size_t)eg * 256 + tid] = (f16)((eg < N_EDGES) ? fmaxf(acc2[e], 0.f) : 0.f);
    }
}

// ---- G-tile + message + scatter-mean ----------------------------------------
// block = 32 nodes x 8 output-cols (og). Phase 1: G[n][o][k] = sum_i h16[n][i] *
// Mp2[(og*8+o)*256+k][i] via MFMA into 128 KB LDS (XOR-swizzled k-granules).
// Phase 2: for this node-group's out-edges (src-CSR), msg[e][o] =
// sum_k k2[e][k]*G[..] via fdot2, + hb bias, * dinv, atomic into agg.
__global__ __launch_bounds__(256) void k_gmsg(const f16* __restrict__ k2, const f16* __restrict__ Mp2,
                                              const f16* __restrict__ h16, const float* __restrict__ hb,
                                              const int* __restrict__ ei, const int* __restrict__ srcPtr,
                                              const int* __restrict__ srcIdx, const float* __restrict__ dinv,
                                              float* __restrict__ agg) {
    __shared__ __align__(16) f16 G[32 * 8 * 256];   // 128 KB
    char* Gb = (char*)G;
    int tid = threadIdx.x, wave = tid >> 6, lane = tid & 63;
    int n0 = blockIdx.x * 32;
    int og = blockIdx.y;
    // ---- phase 1: each wave owns 512 c-cols (= 2 o values), 32 n-frags ------
    f16x8 a[2][2];
#pragma unroll
    for (int mf = 0; mf < 2; ++mf)
#pragma unroll
        for (int ks = 0; ks < 2; ++ks)
            a[mf][ks] = *(const f16x8*)(h16 + (size_t)(n0 + mf * 16 + (lane & 15)) * 64 + ks * 32 + (lane >> 4) * 8);
    const f16* Brow = Mp2 + ((size_t)og * 2048 + wave * 512 + (lane & 15)) * 64 + (lane >> 4) * 8;
    // 2-deep B prefetch pipeline (named regs, static indexing)
    f16x8 p0a = *(const f16x8*)(Brow);
    f16x8 p0b = *(const f16x8*)(Brow + 32);
    f16x8 p1a = *(const f16x8*)(Brow + 1024);
    f16x8 p1b = *(const f16x8*)(Brow + 1024 + 32);
#pragma unroll 1
    for (int nf = 0; nf < 32; ++nf) {
        f16x8 c0 = p0a, c1 = p0b;
        p0a = p1a; p0b = p1b;
        if (nf < 30) {
            p1a = *(const f16x8*)(Brow + (nf + 2) * 1024);
            p1b = *(const f16x8*)(Brow + (nf + 2) * 1024 + 32);
        }
        f32x4 acc0 = {}, acc1 = {};
        acc0 = __builtin_amdgcn_mfma_f32_16x16x32_f16(a[0][0], c0, acc0, 0, 0, 0);
        acc0 = __builtin_amdgcn_mfma_f32_16x16x32_f16(a[0][1], c1, acc0, 0, 0, 0);
        acc1 = __builtin_amdgcn_mfma_f32_16x16x32_f16(a[1][0], c0, acc1, 0, 0, 0);
        acc1 = __builtin_amdgcn_mfma_f32_16x16x32_f16(a[1][1], c1, acc1, 0, 0, 0);
        int olocal = wave * 2 + (nf >> 4);
        int kk = ((nf & 15) << 4) + (lane & 15);
        int gq = kk >> 3, grb = (kk & 7) * 2;
#pragma unroll
        for (int jj = 0; jj < 4; ++jj) {
            int ro0 = ((lane >> 4) * 4 + jj) * 8 + olocal;          // mf = 0
            *(f16*)(Gb + ro0 * 512 + ((gq ^ (ro0 & 31)) << 4) + grb) = (f16)acc0[jj];
            int ro1 = (16 + (lane >> 4) * 4 + jj) * 8 + olocal;     // mf = 1
            *(f16*)(Gb + ro1 * 512 + ((gq ^ (ro1 & 31)) << 4) + grb) = (f16)acc1[jj];
        }
    }
    __syncthreads();
    // ---- phase 2: edges with src in [n0, n0+32) -----------------------------
    int sp0 = srcPtr[n0];
    int cnt8 = (srcPtr[n0 + 32] - sp0) << 3;
#pragma unroll 1
    for (int p = tid; p < cnt8; p += 256) {
        int e = srcIdx[sp0 + (p >> 3)];
        int o = p & 7;
        int sn = ei[e];
        int ro = (sn - n0) * 8 + o, s = ro & 31;
        const char* gbase = Gb + ro * 512;
        const f16* kp = k2 + (size_t)e * 256;
        float m = 0.f;
#pragma unroll 4
        for (int kc = 0; kc < 32; ++kc) {
            f16x8 kv = *(const f16x8*)(kp + kc * 8);
            f16x8 gv = *(const f16x8*)(gbase + ((kc ^ s) << 4));
            m = FDOT2(SV2(kv, 0), SV2(gv, 0), m);
            m = FDOT2(SV2(kv, 1), SV2(gv, 1), m);
            m = FDOT2(SV2(kv, 2), SV2(gv, 2), m);
            m = FDOT2(SV2(kv, 3), SV2(gv, 3), m);
        }
        int ogo = (og << 3) + o;
        int d = ei[N_EDGES + e];
        atomicAdd(&agg[(size_t)d * 64 + ogo], (m + hb[(size_t)sn * 64 + ogo]) * dinv[d]);
    }
}

// ---------------- node update: h' = relu(agg + h@root + bias) (+f16) ---------
__global__ void k_update(const float* __restrict__ agg, const float* __restrict__ h,
                         const float* __restrict__ root, const float* __restrict__ bias,
                         float* __restrict__ hn, f16* __restrict__ hn16) {
    __shared__ float t[4][64];
    int g = threadIdx.x >> 6, j = threadIdx.x & 63;
    int node = blockIdx.x * 4 + g;
    t[g][j] = h[node * 64 + j];
    __syncthreads();
    float acc = agg[node * 64 + j] + bias[j];
#pragma unroll
    for (int i = 0; i < 64; ++i) acc += t[g][i] * root[i * 64 + j];
    float v = fmaxf(acc, 0.f);
    hn[node * 64 + j] = v;
    hn16[node * 64 + j] = (f16)v;
}

// ---------------- output head ------------------------------------------------
__global__ void k_out(const float* __restrict__ h, const float* __restrict__ oW,
                      const float* __restrict__ ob, float* __restrict__ out) {
    int wg = (blockIdx.x * 256 + threadIdx.x) >> 6;
    int lane = threadIdx.x & 63;
    if (wg >= N_NODES) return;
    float p = h[wg * 64 + lane] * oW[lane];
#pragma unroll
    for (int s = 32; s > 0; s >>= 1) p += __shfl_xor(p, s);
    if (lane == 0) out[wg] = p + ob[0];
}

__global__ void k_sentinel(float* out) { out[0] = 1e30f; }

extern "C" void kernel_launch(void* const* d_in, const int* in_sizes, int n_in,
                              void* d_out, int out_size, void* d_ws, size_t ws_size,
                              hipStream_t stream) {
    const float* x          = (const float*)d_in[0];
    const float* edge_attr  = (const float*)d_in[1];
    const float* conditions = (const float*)d_in[2];
    const float* scale      = (const float*)d_in[3];
    const int*   edge_index = (const int*)d_in[4];
    const int*   batch      = (const int*)d_in[5];
    const float* nW1 = (const float*)d_in[6];  const float* nb1 = (const float*)d_in[7];
    const float* nW2 = (const float*)d_in[8];  const float* nb2 = (const float*)d_in[9];
    const float* cW1 = (const float*)d_in[10]; const float* cb1 = (const float*)d_in[11];
    const float* cW2 = (const float*)d_in[12]; const float* cb2 = (const float*)d_in[13];
    const float* kW1 = (const float*)d_in[14]; const float* kb1 = (const float*)d_in[15];
    const float* kW2 = (const float*)d_in[16]; const float* kb2 = (const float*)d_in[17];
    const float* kW3 = (const float*)d_in[18]; const float* kb3 = (const float*)d_in[19];
    const float* root = (const float*)d_in[20]; const float* conv_bias = (const float*)d_in[21];
    const float* oW  = (const float*)d_in[22]; const float* ob  = (const float*)d_in[23];
    float* out = (float*)d_out;

    char* ws = (char*)d_ws;
    size_t off = 0;
    auto alloc = [&](size_t bytes) -> char* {
        char* p = ws + off;
        off += (bytes + 255) & ~(size_t)255;
        return p;
    };
    float* h_a   = (float*)alloc((size_t)N_NODES * 64 * 4);
    float* h_b   = (float*)alloc((size_t)N_NODES * 64 * 4);
    f16*   h16_a = (f16*)alloc((size_t)NPAD * 64 * 2);
    f16*   h16_b = (f16*)alloc((size_t)NPAD * 64 * 2);
    float* agg   = (float*)alloc((size_t)N_NODES * 64 * 4);
    float* hb    = (float*)alloc((size_t)N_NODES * 64 * 4);
    float* u     = (float*)alloc(256 * 4);
    float* deg   = (float*)alloc((size_t)N_NODES * 4);
    int*   cnt   = (int*)alloc((size_t)NPAD * 4);
    int*   srcPtr= (int*)alloc((size_t)(NPAD + 1) * 4);
    int*   cursor= (int*)alloc((size_t)(NPAD + 1) * 4);
    int*   srcIdx= (int*)alloc((size_t)N_EDGES * 4);
    f16*   k2    = (f16*)alloc((size_t)EPAD * 256 * 2);
    f16*   Mp2   = (f16*)alloc((size_t)16384 * 64 * 2);
    // total ~48 MB

    if (off > ws_size) {  // workspace too small: distinct sentinel
        k_sentinel<<<1, 1, 0, stream>>>(out);
        return;
    }

    hipMemsetAsync(deg, 0, (size_t)N_NODES * 4, stream);
    hipMemsetAsync(cnt, 0, (size_t)NPAD * 4, stream);
    k_node_enc<<<2500, 256, 0, stream>>>(x, nW1, nb1, nW2, nb2, h_a, h16_a);
    k_cond_enc<<<1, 256, 0, stream>>>(conditions, scale, cW1, cb1, cW2, cb2, u, out + N_NODES);
    k_deg<<<(N_EDGES + 255) / 256, 256, 0, stream>>>(edge_index + N_EDGES, deg);
    k_deg_inv<<<(N_NODES + 255) / 256, 256, 0, stream>>>(deg);
    k_csr_count<<<(N_EDGES + 255) / 256, 256, 0, stream>>>(edge_index, cnt);
    k_csr_scan<<<1, 256, 0, stream>>>(cnt, srcPtr, cursor);
    k_csr_fill<<<(N_EDGES + 255) / 256, 256, 0, stream>>>(edge_index, cursor, srcIdx);
    k_mp2<<<dim3(64, 8), 256, 0, stream>>>(kW3, Mp2);
    k_edge12<<<EPAD / 16, 256, 0, stream>>>(edge_attr, edge_index, batch, u, kW1, kb1, kW2, kb2, k2);

    float* hc = h_a; float* hn = h_b;
    f16* hc16 = h16_a; f16* hn16 = h16_b;
    for (int l = 0; l < 3; ++l) {
        hipMemsetAsync(agg, 0, (size_t)N_NODES * 64 * 4, stream);
        k_hb<<<2500, 256, 0, stream>>>(hc, kb3, hb);
        k_gmsg<<<dim3(NPAD / 32, 8), 256, 0, stream>>>(k2, Mp2, hc16, hb, edge_index,
                                                       srcPtr, srcIdx, deg, agg);
        k_update<<<2500, 256, 0, stream>>>(agg, hc, root, conv_bias, hn, hn16);
        float* tf = hc; hc = hn; hn = tf;
        f16* t16 = hc16; hc16 = hn16; hn16 = t16;
    }
    k_out<<<2500, 256, 0, stream>>>(hc, oW, ob, out);
}

// Round 14
// 955.576 us; speedup vs baseline: 3.8948x; 1.2949x over previous
//
#include <hip/hip_runtime.h>
#include <hip/hip_fp16.h>

#define N_NODES 10000
#define NPAD    10016   // multiple of 16
#define N_EDGES 60000
#define EPAD    60032

typedef _Float16 f16;
typedef f16 f16x8 __attribute__((ext_vector_type(8)));
typedef f16 f16x2 __attribute__((ext_vector_type(2)));
typedef float f32x4 __attribute__((ext_vector_type(4)));

#define SV2(v, j) __builtin_shufflevector(v, v, 2 * (j), 2 * (j) + 1)

#if __has_builtin(__builtin_amdgcn_fdot2)
__device__ __forceinline__ float FDOT2(f16x2 a, f16x2 b, float c) {
    return __builtin_amdgcn_fdot2(a, b, c, false);
}
#else
__device__ __forceinline__ float FDOT2(f16x2 a, f16x2 b, float c) {
    return c + (float)a[0] * (float)b[0] + (float)a[1] * (float)b[1];
}
#endif

// ---------------- node encoder: h = relu(x@nW1+nb1)@nW2+nb2 (+f16 copy) ----
__global__ void k_node_enc(const float* __restrict__ x, const float* __restrict__ W1,
                           const float* __restrict__ b1, const float* __restrict__ W2,
                           const float* __restrict__ b2, float* __restrict__ h,
                           f16* __restrict__ h16) {
    __shared__ float t[4][64];
    int g = threadIdx.x >> 6, j = threadIdx.x & 63;
    int node = blockIdx.x * 4 + g;
    float acc = b1[j];
#pragma unroll
    for (int i = 0; i < 6; ++i) acc += x[node * 6 + i] * W1[i * 64 + j];
    t[g][j] = fmaxf(acc, 0.f);
    __syncthreads();
    float acc2 = b2[j];
#pragma unroll
    for (int i = 0; i < 64; ++i) acc2 += t[g][i] * W2[i * 64 + j];
    h[node * 64 + j] = acc2;
    h16[node * 64 + j] = (f16)acc2;
}

// ---------------- condition encoder -----------------------------------------
__global__ void k_cond_enc(const float* __restrict__ cond, const float* __restrict__ scl,
                           const float* __restrict__ W1, const float* __restrict__ b1,
                           const float* __restrict__ W2, const float* __restrict__ b2,
                           float* __restrict__ u, float* __restrict__ out_u) {
    __shared__ float t[4][64];
    __shared__ float cat[4][14];
    int g = threadIdx.x >> 6, j = threadIdx.x & 63;
    if (threadIdx.x < 56) {
        int b = threadIdx.x / 14, i = threadIdx.x % 14;
        cat[b][i] = (i < 10) ? cond[b * 10 + i] : scl[b * 4 + (i - 10)];
    }
    __syncthreads();
    float acc = b1[j];
#pragma unroll
    for (int i = 0; i < 14; ++i) acc += cat[g][i] * W1[i * 64 + j];
    t[g][j] = fmaxf(acc, 0.f);
    __syncthreads();
    float acc2 = b2[j];
#pragma unroll
    for (int i = 0; i < 64; ++i) acc2 += t[g][i] * W2[i * 64 + j];
    u[g * 64 + j] = acc2;
    out_u[g * 64 + j] = acc2;
}

// ---------------- degree -----------------------------------------------------
__global__ void k_deg(const int* __restrict__ dst, float* __restrict__ deg) {
    int e = blockIdx.x * 256 + threadIdx.x;
    if (e < N_EDGES) atomicAdd(&deg[dst[e]], 1.0f);
}
__global__ void k_deg_inv(float* __restrict__ deg) {
    int n = blockIdx.x * 256 + threadIdx.x;
    if (n < N_NODES) deg[n] = 1.0f / fmaxf(deg[n], 1.0f);
}

// ---------------- src-CSR build ----------------------------------------------
__global__ void k_csr_count(const int* __restrict__ src, int* __restrict__ cnt) {
    int e = blockIdx.x * 256 + threadIdx.x;
    if (e < N_EDGES) atomicAdd(&cnt[src[e]], 1);
}
__global__ void k_csr_scan(const int* __restrict__ cnt, int* __restrict__ srcPtr,
                           int* __restrict__ cursor) {
    __shared__ int part[256];
    int t = threadIdx.x;
    int base = t * 40;
    int s = 0;
#pragma unroll 1
    for (int i = 0; i < 40; ++i) { int idx = base + i; if (idx < NPAD) s += cnt[idx]; }
    part[t] = s;
    __syncthreads();
    if (t == 0) {
        int run = 0;
        for (int i = 0; i < 256; ++i) { int v = part[i]; part[i] = run; run += v; }
    }
    __syncthreads();
    int run = part[t];
#pragma unroll 1
    for (int i = 0; i < 40; ++i) {
        int idx = base + i;
        if (idx <= NPAD) {
            srcPtr[idx] = run; cursor[idx] = run;
            if (idx < NPAD) run += cnt[idx];
        }
    }
}
__global__ void k_csr_fill(const int* __restrict__ src, int* __restrict__ cursor,
                           int* __restrict__ srcIdx) {
    int e = blockIdx.x * 256 + threadIdx.x;
    if (e < N_EDGES) { int p = atomicAdd(&cursor[src[e]], 1); srcIdx[p] = e; }
}

// ------- permute kW3 -> Mp2[c][i] = kW3[k][i*64+o], c = o*256+k, f16 ---------
__global__ void k_mp2(const float* __restrict__ kW3, f16* __restrict__ Mp2) {
    int k = threadIdx.x, o = blockIdx.x, ib = blockIdx.y;
#pragma unroll
    for (int j = 0; j < 8; ++j) {
        int i = ib * 8 + j;
        Mp2[((size_t)o * 256 + k) * 64 + i] = (f16)kW3[(size_t)k * 4096 + i * 64 + o];
    }
}

// ---------------- hb[n][o] = sum_i h[n][i]*kb3[i*64+o] (bias term) ----------
__global__ void k_hb(const float* __restrict__ h, const float* __restrict__ kb3,
                     float* __restrict__ hb) {
    __shared__ float t[4][64];
    int g = threadIdx.x >> 6, j = threadIdx.x & 63;
    int node = blockIdx.x * 4 + g;
    t[g][j] = h[node * 64 + j];
    __syncthreads();
    float acc = 0.f;
#pragma unroll
    for (int i = 0; i < 64; ++i) acc += t[g][i] * kb3[i * 64 + j];
    hb[node * 64 + j] = acc;
}

// ---------------- fused edge MLP (k1 in LDS, k2 fp16 out) --------------------
__global__ __launch_bounds__(256) void k_edge12(const float* __restrict__ ea, const int* __restrict__ ei,
                                                const int* __restrict__ batch, const float* __restrict__ u,
                                                const float* __restrict__ W1, const float* __restrict__ b1,
                                                const float* __restrict__ W2, const float* __restrict__ b2,
                                                f16* __restrict__ k2) {
    __shared__ float u_s[256];
    __shared__ float ea_s[16][6];
    __shared__ int b_s[16];
    __shared__ float k1_s[16][128];
    int tid = threadIdx.x;
    int e0 = blockIdx.x * 16;
    u_s[tid] = u[tid];
    if (tid < 96) {
        int e = tid / 6, i = tid % 6;
        int eg = e0 + e;
        ea_s[e][i] = (eg < N_EDGES) ? ea[(size_t)eg * 6 + i] : 0.f;
    }
    if (tid < 16) {
        int eg = e0 + tid;
        b_s[tid] = (eg < N_EDGES) ? batch[ei[eg]] : 0;
    }
    __syncthreads();
    int j = tid & 127;
#pragma unroll 1
    for (int p = 0; p < 8; ++p) {
        int e = p * 2 + (tid >> 7);
        float acc = b1[j];
#pragma unroll
        for (int i = 0; i < 6; ++i) acc += ea_s[e][i] * W1[i * 128 + j];
        const float* ur = u_s + b_s[e] * 64;
#pragma unroll
        for (int i = 0; i < 64; ++i) acc += ur[i] * W1[(6 + i) * 128 + j];
        k1_s[e][j] = fmaxf(acc, 0.f);
    }
    __syncthreads();
    float acc2[16];
#pragma unroll
    for (int e = 0; e < 16; ++e) acc2[e] = b2[tid];
    for (int i = 0; i < 128; ++i) {
        float w = W2[(size_t)i * 256 + tid];
#pragma unroll
        for (int e = 0; e < 16; ++e) acc2[e] += k1_s[e][i] * w;
    }
#pragma unroll
    for (int e = 0; e < 16; ++e) {
        int eg = e0 + e;
        k2[(size_t)eg * 256 + tid] = (f16)((eg < N_EDGES) ? fmaxf(acc2[e], 0.f) : 0.f);
    }
}

// ---- G-tile + message + scatter-mean ----------------------------------------
// block = 16 nodes x 8 output-cols (og) -> G tile 64 KB -> 2 blocks/CU.
// Phase 1: G[n][o][k] = sum_i h16[n][i]*Mp2[(og*8+o)*256+k][i] via MFMA.
// Phase 2: per (out-edge, o): 256-k dot via fdot2 with 8 independent
// accumulator chains (ILP), + hb bias, * dinv, atomic into agg.
__global__ __launch_bounds__(256) void k_gmsg(const f16* __restrict__ k2, const f16* __restrict__ Mp2,
                                              const f16* __restrict__ h16, const float* __restrict__ hb,
                                              const int* __restrict__ ei, const int* __restrict__ srcPtr,
                                              const int* __restrict__ srcIdx, const float* __restrict__ dinv,
                                              float* __restrict__ agg) {
    __shared__ __align__(16) f16 G[16 * 8 * 256];   // 64 KB
    char* Gb = (char*)G;
    int tid = threadIdx.x, wave = tid >> 6, lane = tid & 63;
    int n0 = blockIdx.x * 16;
    int og = blockIdx.y;
    // ---- phase 1: each wave owns 512 c-cols (= 2 o values), 16 node rows ----
    f16x8 a0 = *(const f16x8*)(h16 + (size_t)(n0 + (lane & 15)) * 64 + (lane >> 4) * 8);
    f16x8 a1 = *(const f16x8*)(h16 + (size_t)(n0 + (lane & 15)) * 64 + 32 + (lane >> 4) * 8);
    const f16* Brow = Mp2 + ((size_t)og * 2048 + wave * 512 + (lane & 15)) * 64 + (lane >> 4) * 8;
    // 2-deep B prefetch pipeline (named regs, static indexing)
    f16x8 p0a = *(const f16x8*)(Brow);
    f16x8 p0b = *(const f16x8*)(Brow + 32);
    f16x8 p1a = *(const f16x8*)(Brow + 1024);
    f16x8 p1b = *(const f16x8*)(Brow + 1024 + 32);
#pragma unroll 1
    for (int nf = 0; nf < 32; ++nf) {
        f16x8 c0 = p0a, c1 = p0b;
        p0a = p1a; p0b = p1b;
        if (nf < 30) {
            p1a = *(const f16x8*)(Brow + (nf + 2) * 1024);
            p1b = *(const f16x8*)(Brow + (nf + 2) * 1024 + 32);
        }
        f32x4 acc = {};
        acc = __builtin_amdgcn_mfma_f32_16x16x32_f16(a0, c0, acc, 0, 0, 0);
        acc = __builtin_amdgcn_mfma_f32_16x16x32_f16(a1, c1, acc, 0, 0, 0);
        int olocal = wave * 2 + (nf >> 4);
        int kk = ((nf & 15) << 4) + (lane & 15);
        int gq = kk >> 3, grb = (kk & 7) * 2;
#pragma unroll
        for (int jj = 0; jj < 4; ++jj) {
            int ro = ((lane >> 4) * 4 + jj) * 8 + olocal;
            *(f16*)(Gb + ro * 512 + ((gq ^ (ro & 31)) << 4) + grb) = (f16)acc[jj];
        }
    }
    __syncthreads();
    // ---- phase 2: edges with src in [n0, n0+16) -----------------------------
    int sp0 = srcPtr[n0];
    int cnt8 = (srcPtr[n0 + 16] - sp0) << 3;
#pragma unroll 1
    for (int p = tid; p < cnt8; p += 256) {
        int e = srcIdx[sp0 + (p >> 3)];
        int o = p & 7;
        int sn = ei[e];
        int ro = (sn - n0) * 8 + o, s = ro & 31;
        const char* gbase = Gb + ro * 512;
        const f16* kp = k2 + (size_t)e * 256;
        float m0 = 0.f, m1 = 0.f, m2 = 0.f, m3 = 0.f;
        float m4 = 0.f, m5 = 0.f, m6 = 0.f, m7 = 0.f;
#define CHUNK(kc, M) { f16x8 kv = *(const f16x8*)(kp + (kc) * 8); \
        f16x8 gv = *(const f16x8*)(gbase + (((kc) ^ s) << 4)); \
        M = FDOT2(SV2(kv, 0), SV2(gv, 0), M); M = FDOT2(SV2(kv, 1), SV2(gv, 1), M); \
        M = FDOT2(SV2(kv, 2), SV2(gv, 2), M); M = FDOT2(SV2(kv, 3), SV2(gv, 3), M); }
        CHUNK(0, m0)  CHUNK(1, m1)  CHUNK(2, m2)  CHUNK(3, m3)
        CHUNK(4, m4)  CHUNK(5, m5)  CHUNK(6, m6)  CHUNK(7, m7)
        CHUNK(8, m0)  CHUNK(9, m1)  CHUNK(10, m2) CHUNK(11, m3)
        CHUNK(12, m4) CHUNK(13, m5) CHUNK(14, m6) CHUNK(15, m7)
        CHUNK(16, m0) CHUNK(17, m1) CHUNK(18, m2) CHUNK(19, m3)
        CHUNK(20, m4) CHUNK(21, m5) CHUNK(22, m6) CHUNK(23, m7)
        CHUNK(24, m0) CHUNK(25, m1) CHUNK(26, m2) CHUNK(27, m3)
        CHUNK(28, m4) CHUNK(29, m5) CHUNK(30, m6) CHUNK(31, m7)
#undef CHUNK
        float m = ((m0 + m1) + (m2 + m3)) + ((m4 + m5) + (m6 + m7));
        int ogo = (og << 3) + o;
        int d = ei[N_EDGES + e];
        atomicAdd(&agg[(size_t)d * 64 + ogo], (m + hb[(size_t)sn * 64 + ogo]) * dinv[d]);
    }
}

// ---------------- node update: h' = relu(agg + h@root + bias) (+f16) ---------
__global__ void k_update(const float* __restrict__ agg, const float* __restrict__ h,
                         const float* __restrict__ root, const float* __restrict__ bias,
                         float* __restrict__ hn, f16* __restrict__ hn16) {
    __shared__ float t[4][64];
    int g = threadIdx.x >> 6, j = threadIdx.x & 63;
    int node = blockIdx.x * 4 + g;
    t[g][j] = h[node * 64 + j];
    __syncthreads();
    float acc = agg[node * 64 + j] + bias[j];
#pragma unroll
    for (int i = 0; i < 64; ++i) acc += t[g][i] * root[i * 64 + j];
    float v = fmaxf(acc, 0.f);
    hn[node * 64 + j] = v;
    hn16[node * 64 + j] = (f16)v;
}

// ---------------- output head ------------------------------------------------
__global__ void k_out(const float* __restrict__ h, const float* __restrict__ oW,
                      const float* __restrict__ ob, float* __restrict__ out) {
    int wg = (blockIdx.x * 256 + threadIdx.x) >> 6;
    int lane = threadIdx.x & 63;
    if (wg >= N_NODES) return;
    float p = h[wg * 64 + lane] * oW[lane];
#pragma unroll
    for (int s = 32; s > 0; s >>= 1) p += __shfl_xor(p, s);
    if (lane == 0) out[wg] = p + ob[0];
}

__global__ void k_sentinel(float* out) { out[0] = 1e30f; }

extern "C" void kernel_launch(void* const* d_in, const int* in_sizes, int n_in,
                              void* d_out, int out_size, void* d_ws, size_t ws_size,
                              hipStream_t stream) {
    const float* x          = (const float*)d_in[0];
    const float* edge_attr  = (const float*)d_in[1];
    const float* conditions = (const float*)d_in[2];
    const float* scale      = (const float*)d_in[3];
    const int*   edge_index = (const int*)d_in[4];
    const int*   batch      = (const int*)d_in[5];
    const float* nW1 = (const float*)d_in[6];  const float* nb1 = (const float*)d_in[7];
    const float* nW2 = (const float*)d_in[8];  const float* nb2 = (const float*)d_in[9];
    const float* cW1 = (const float*)d_in[10]; const float* cb1 = (const float*)d_in[11];
    const float* cW2 = (const float*)d_in[12]; const float* cb2 = (const float*)d_in[13];
    const float* kW1 = (const float*)d_in[14]; const float* kb1 = (const float*)d_in[15];
    const float* kW2 = (const float*)d_in[16]; const float* kb2 = (const float*)d_in[17];
    const float* kW3 = (const float*)d_in[18]; const float* kb3 = (const float*)d_in[19];
    const float* root = (const float*)d_in[20]; const float* conv_bias = (const float*)d_in[21];
    const float* oW  = (const float*)d_in[22]; const float* ob  = (const float*)d_in[23];
    float* out = (float*)d_out;

    char* ws = (char*)d_ws;
    size_t off = 0;
    auto alloc = [&](size_t bytes) -> char* {
        char* p = ws + off;
        off += (bytes + 255) & ~(size_t)255;
        return p;
    };
    float* h_a   = (float*)alloc((size_t)N_NODES * 64 * 4);
    float* h_b   = (float*)alloc((size_t)N_NODES * 64 * 4);
    f16*   h16_a = (f16*)alloc((size_t)NPAD * 64 * 2);
    f16*   h16_b = (f16*)alloc((size_t)NPAD * 64 * 2);
    float* agg   = (float*)alloc((size_t)N_NODES * 64 * 4);
    float* hb    = (float*)alloc((size_t)N_NODES * 64 * 4);
    float* u     = (float*)alloc(256 * 4);
    float* deg   = (float*)alloc((size_t)N_NODES * 4);
    int*   cnt   = (int*)alloc((size_t)NPAD * 4);
    int*   srcPtr= (int*)alloc((size_t)(NPAD + 1) * 4);
    int*   cursor= (int*)alloc((size_t)(NPAD + 1) * 4);
    int*   srcIdx= (int*)alloc((size_t)N_EDGES * 4);
    f16*   k2    = (f16*)alloc((size_t)EPAD * 256 * 2);
    f16*   Mp2   = (f16*)alloc((size_t)16384 * 64 * 2);
    // total ~48 MB

    if (off > ws_size) {  // workspace too small: distinct sentinel
        k_sentinel<<<1, 1, 0, stream>>>(out);
        return;
    }

    hipMemsetAsync(deg, 0, (size_t)N_NODES * 4, stream);
    hipMemsetAsync(cnt, 0, (size_t)NPAD * 4, stream);
    k_node_enc<<<2500, 256, 0, stream>>>(x, nW1, nb1, nW2, nb2, h_a, h16_a);
    k_cond_enc<<<1, 256, 0, stream>>>(conditions, scale, cW1, cb1, cW2, cb2, u, out + N_NODES);
    k_deg<<<(N_EDGES + 255) / 256, 256, 0, stream>>>(edge_index + N_EDGES, deg);
    k_deg_inv<<<(N_NODES + 255) / 256, 256, 0, stream>>>(deg);
    k_csr_count<<<(N_EDGES + 255) / 256, 256, 0, stream>>>(edge_index, cnt);
    k_csr_scan<<<1, 256, 0, stream>>>(cnt, srcPtr, cursor);
    k_csr_fill<<<(N_EDGES + 255) / 256, 256, 0, stream>>>(edge_index, cursor, srcIdx);
    k_mp2<<<dim3(64, 8), 256, 0, stream>>>(kW3, Mp2);
    k_edge12<<<EPAD / 16, 256, 0, stream>>>(edge_attr, edge_index, batch, u, kW1, kb1, kW2, kb2, k2);

    float* hc = h_a; float* hn = h_b;
    f16* hc16 = h16_a; f16* hn16 = h16_b;
    for (int l = 0; l < 3; ++l) {
        hipMemsetAsync(agg, 0, (size_t)N_NODES * 64 * 4, stream);
        k_hb<<<2500, 256, 0, stream>>>(hc, kb3, hb);
        k_gmsg<<<dim3(NPAD / 16, 8), 256, 0, stream>>>(k2, Mp2, hc16, hb, edge_index,
                                                       srcPtr, srcIdx, deg, agg);
        k_update<<<2500, 256, 0, stream>>>(agg, hc, root, conv_bias, hn, hn16);
        float* tf = hc; hc = hn; hn = tf;
        f16* t16 = hc16; hc16 = hn16; hn16 = t16;
    }
    k_out<<<2500, 256, 0, stream>>>(hc, oW, ob, out);
}